// Round 9
// baseline (134.621 us; speedup 1.0000x reference)
//
#include <hip/hip_runtime.h>

// Head: k = x@Wk^T; q = k (source bug); wei = softmax(causal(q k^T / 8)); v = x@Wv^T; out = wei@v
// B=8, T=2048, C=1024, H=64. fp32 in/out, bf16 MFMA internally.
//
// R8 -> R9: attn loop-nest inverted (triangle tiling). Block (b,J,P) stages KV rows
// [2J*64, 2J*64+128) ONCE (one barrier per block), then computes q-tiles qb=2P,2P+1
// (P>=J) from LDS; partials keyed (b,qb,J), combine sums qb/2+1 of them. Removes all
// per-iter barriers + 75% of K/V staging. proj/wconv unchanged from R8.

typedef __bf16 bf16;
typedef __bf16 bf16x4 __attribute__((ext_vector_type(4)));
typedef __bf16 bf16x8 __attribute__((ext_vector_type(8)));
typedef float  floatx4 __attribute__((ext_vector_type(4)));

#define T_LEN 2048
#define HEAD  64
#define CEMB  1024

static __device__ __forceinline__ void async16(const void* g, void* l) {
    __builtin_amdgcn_global_load_lds(
        (const __attribute__((address_space(1))) void*)g,
        (__attribute__((address_space(3))) void*)l, 16, 0, 0);
}

static __device__ __forceinline__ bf16x8 cvt2(float4 a, float4 b) {
    bf16x8 r;
    r[0] = (bf16)a.x; r[1] = (bf16)a.y; r[2] = (bf16)a.z; r[3] = (bf16)a.w;
    r[4] = (bf16)b.x; r[5] = (bf16)b.y; r[6] = (bf16)b.z; r[7] = (bf16)b.w;
    return r;
}
static __device__ __forceinline__ bf16x4 cvt1(float4 a) {
    bf16x4 r;
    r[0] = (bf16)a.x; r[1] = (bf16)a.y; r[2] = (bf16)a.z; r[3] = (bf16)a.w;
    return r;
}

// ---------------- Kernel 0: W fp32 -> bf16, [Wk;Wv] concat as Wb[128][1024]
__global__ __launch_bounds__(256) void wconv_kernel(const float* __restrict__ Wk,
                                                    const float* __restrict__ Wv,
                                                    bf16* __restrict__ Wb) {
    int i = (blockIdx.x * 256 + threadIdx.x) * 4;   // grid 128 covers 131072
    const float* src = (i < 64 * 1024) ? (Wk + i) : (Wv + (i - 64 * 1024));
    *(bf16x4*)&Wb[i] = cvt1(*(const float4*)src);
}

// ---------------- Kernel 1: projection GEMM (unchanged from R8). grid 512,
// tile 32x128, BK=64, DMA double-buffered, XOR-swizzled LDS.
__global__ __launch_bounds__(256) void proj_kernel(const float* __restrict__ x,
                                                   const bf16* __restrict__ Wb,
                                                   bf16* __restrict__ Kbuf,
                                                   bf16* __restrict__ Vt) {
    __shared__ __align__(16) float As[2][32 * 64];
    __shared__ __align__(16) bf16  Bs[2][128 * 64];

    const int tid  = threadIdx.x;
    const int wave = tid >> 6;
    const int lane = tid & 63;
    const int quad = lane >> 4;
    const int low  = lane & 15;

    const long row0 = (long)blockIdx.x * 32;

    const int ar_ = lane >> 4;
    const int ac_ = (lane & 15) ^ (wave * 4 + ar_);
    const int br_ = lane >> 3;
    const int bc_ = (lane & 7) ^ br_;

    const int strip = wave & 1;
    const int nq    = (wave >> 1) * 4;

    floatx4 acc[4];
#pragma unroll
    for (int i = 0; i < 4; ++i) acc[i] = (floatx4){0.f, 0.f, 0.f, 0.f};

    auto stage = [&](int s, int sb) {
        const int k0 = s * 64;
#pragma unroll
        for (int m = 0; m < 2; ++m) {
            const int r = (m * 4 + wave) * 4 + ar_;
            async16(x + (row0 + r) * CEMB + k0 + ac_ * 4, &As[sb][(m * 4 + wave) * 256]);
        }
#pragma unroll
        for (int m = 0; m < 4; ++m) {
            const int r = (m * 4 + wave) * 8 + br_;
            async16(Wb + r * CEMB + k0 + bc_ * 8, &Bs[sb][(m * 4 + wave) * 512]);
        }
    };

    stage(0, 0);
    stage(1, 1);
    __syncthreads();

    int buf = 0;
    for (int s = 0; s < 16; ++s) {
#pragma unroll
        for (int ks = 0; ks < 2; ++ks) {
            const int rr = strip * 16 + low;
            const int c0 = ks * 8 + quad * 2;
            float4 a0 = *(const float4*)&As[buf][rr * 64 + ((c0 ^ low) * 4)];
            float4 a1 = *(const float4*)&As[buf][rr * 64 + (((c0 + 1) ^ low) * 4)];
            bf16x8 afrag = cvt2(a0, a1);
            const int cq = ks * 4 + quad;
#pragma unroll
            for (int i = 0; i < 4; ++i) {
                const int r2 = (nq + i) * 16 + low;
                bf16x8 bfrag = *(const bf16x8*)&Bs[buf][r2 * 64 + ((cq ^ (low & 7)) * 8)];
                acc[i] = __builtin_amdgcn_mfma_f32_16x16x32_bf16(afrag, bfrag, acc[i], 0, 0, 0);
            }
        }
        if (s < 15) {
            __syncthreads();
            if (s < 14) stage(s + 2, buf);
            buf ^= 1;
        }
    }

    __syncthreads();
    bf16* Ek = (bf16*)&Bs[0][0];   // [32][72]
    bf16* Ev = (bf16*)&Bs[1][0];   // [64][36]
    if (wave < 2) {
#pragma unroll
        for (int i = 0; i < 4; ++i)
#pragma unroll
            for (int r = 0; r < 4; ++r)
                Ek[(strip * 16 + quad * 4 + r) * 72 + i * 16 + low] = (bf16)acc[i][r];
    } else {
#pragma unroll
        for (int i = 0; i < 4; ++i)
#pragma unroll
            for (int r = 0; r < 4; ++r)
                Ev[(i * 16 + low) * 36 + strip * 16 + quad * 4 + r] = (bf16)acc[i][r];
    }
    __syncthreads();

    const long bidx  = row0 >> 11;
    const int  tloc0 = (int)(row0 & 2047);
    {
        const int t  = tid >> 3;
        const int h0 = (tid & 7) * 8;
        *(bf16x8*)&Kbuf[(bidx * T_LEN + tloc0 + t) * HEAD + h0] = *(const bf16x8*)&Ek[t * 72 + h0];
    }
    {
        const int h  = tid >> 2;
        const int t0 = (tid & 3) * 8;
        *(bf16x8*)&Vt[(bidx * HEAD + h) * T_LEN + tloc0 + t0] = *(const bf16x8*)&Ev[h * 36 + t0];
    }
}

// ---------------- Kernel 2: attention, triangle-tiled. q=k, causal, scale 1/8,
// fixed-max softmax. Block (b, J, P) [P>=J]: stage KV tiles j=2J,2J+1 once;
// compute q-tiles qb=2P,2P+1; write partial per qb at (b,qb,J).
__global__ __launch_bounds__(256) void attn_kernel(const bf16* __restrict__ Kbuf,
                                                   const bf16* __restrict__ Vt,
                                                   bf16* __restrict__ Opart,
                                                   float* __restrict__ lpart) {
    __shared__ __align__(16) bf16 Ks[2][64 * 64];   // swizzled [kv][h], tile jj
    __shared__ __align__(16) bf16 Vs[2][64 * 64];   // swizzled [h][kv], tile jj
    __shared__ __align__(16) bf16 Ps[4][16][72];    // per-wave private (also Eo)

    const int tid  = threadIdx.x;
    const int wave = tid >> 6;
    const int lane = tid & 63;
    const int quad = lane >> 4;
    const int low  = lane & 15;

    // decode block -> (b, J, P), t enumerates {(J,P): 0<=J<=P<16}
    int t = blockIdx.x % 136;
    const int b = blockIdx.x / 136;
    int J = 0;
    while (t >= 16 - J) { t -= 16 - J; ++J; }
    const int P = J + t;

    const bf16* kbase = Kbuf + (long)b * T_LEN * HEAD;
    const bf16* vbase = Vt + (long)b * HEAD * T_LEN;

    // Q fragments for both q-tiles (A-layout) direct from global, issued pre-barrier
    bf16x8 qf[2][2];
#pragma unroll
    for (int tq = 0; tq < 2; ++tq) {
        const bf16* qrow = kbase + ((2 * P + tq) * 64 + wave * 16 + low) * HEAD + quad * 8;
        qf[tq][0] = *(const bf16x8*)(qrow);
        qf[tq][1] = *(const bf16x8*)(qrow + 32);
    }

    // stage K/V tiles 2J, 2J+1 (once)
    const int br_ = lane >> 3;
    const int bc_ = (lane & 7) ^ br_;
#pragma unroll
    for (int jj = 0; jj < 2; ++jj) {
        const int j = 2 * J + jj;
#pragma unroll
        for (int m = 0; m < 2; ++m) {
            const int r = (m * 4 + wave) * 8 + br_;
            async16(kbase + (j * 64 + r) * HEAD + bc_ * 8, &Ks[jj][(m * 4 + wave) * 512]);
            async16(vbase + (long)r * T_LEN + j * 64 + bc_ * 8, &Vs[jj][(m * 4 + wave) * 512]);
        }
    }
    __syncthreads();   // the only barrier

    bf16x8 ones;
#pragma unroll
    for (int i = 0; i < 8; ++i) ones[i] = (bf16)1.0f;

#pragma unroll
    for (int tq = 0; tq < 2; ++tq) {
        const int qb = 2 * P + tq;

        floatx4 o[4], ol;
#pragma unroll
        for (int nt = 0; nt < 4; ++nt) o[nt] = (floatx4){0.f, 0.f, 0.f, 0.f};
        ol = (floatx4){0.f, 0.f, 0.f, 0.f};

#pragma unroll
        for (int jj = 0; jj < 2; ++jj) {
            const int j = 2 * J + jj;
            if (j > qb) continue;   // uniform skip (only diag block, jj=1, tq=0)

            // S = Q K^T from Ks[jj]
            floatx4 s_[4];
#pragma unroll
            for (int nt = 0; nt < 4; ++nt) {
                const int r2 = nt * 16 + low;
                bf16x8 kf0 = *(const bf16x8*)&Ks[jj][r2 * 64 + ((quad ^ (low & 7)) * 8)];
                bf16x8 kf1 = *(const bf16x8*)&Ks[jj][r2 * 64 + (((4 + quad) ^ (low & 7)) * 8)];
                floatx4 z = (floatx4){0.f, 0.f, 0.f, 0.f};
                z = __builtin_amdgcn_mfma_f32_16x16x32_bf16(qf[tq][0], kf0, z, 0, 0, 0);
                z = __builtin_amdgcn_mfma_f32_16x16x32_bf16(qf[tq][1], kf1, z, 0, 0, 0);
                s_[nt] = z;
            }

            // p = exp2(s * 0.125*log2e); mask on diagonal tile; P strip -> LDS (wave-private)
            const bool diag = (j == qb);
#pragma unroll
            for (int nt = 0; nt < 4; ++nt) {
#pragma unroll
                for (int r = 0; r < 4; ++r) {
                    float p = __builtin_amdgcn_exp2f(s_[nt][r] * 0.180336880f);
                    if (diag && (nt * 16 + low) > (wave * 16 + quad * 4 + r)) p = 0.f;
                    Ps[wave][quad * 4 + r][nt * 16 + low] = (bf16)p;
                }
            }

            bf16x8 pf0 = *(const bf16x8*)&Ps[wave][low][quad * 8];
            bf16x8 pf1 = *(const bf16x8*)&Ps[wave][low][32 + quad * 8];
#pragma unroll
            for (int nt = 0; nt < 4; ++nt) {
                const int r2 = nt * 16 + low;
                bf16x8 vf0 = *(const bf16x8*)&Vs[jj][r2 * 64 + ((quad ^ (low & 7)) * 8)];
                bf16x8 vf1 = *(const bf16x8*)&Vs[jj][r2 * 64 + (((4 + quad) ^ (low & 7)) * 8)];
                o[nt] = __builtin_amdgcn_mfma_f32_16x16x32_bf16(pf0, vf0, o[nt], 0, 0, 0);
                o[nt] = __builtin_amdgcn_mfma_f32_16x16x32_bf16(pf1, vf1, o[nt], 0, 0, 0);
            }
            ol = __builtin_amdgcn_mfma_f32_16x16x32_bf16(pf0, ones, ol, 0, 0, 0);
            ol = __builtin_amdgcn_mfma_f32_16x16x32_bf16(pf1, ones, ol, 0, 0, 0);
        }

        // partial store: transpose O through this wave's Ps strip (values consumed), coalesced
        bf16* Eo = (bf16*)&Ps[wave][0][0];   // [16][72], rows = this wave's 16 q-rows
#pragma unroll
        for (int nt = 0; nt < 4; ++nt)
#pragma unroll
            for (int r = 0; r < 4; ++r)
                Eo[(quad * 4 + r) * 72 + nt * 16 + low] = (bf16)o[nt][r];

        const long pidx = ((long)(b * 32 + qb) * 16 + J);
        {
            const int rr   = lane >> 2;          // 0..15 (row within wave strip)
            const int col0 = (lane & 3) * 16;
            bf16* ob = Opart + pidx * 4096 + (wave * 16 + rr) * 64 + col0;
            *(bf16x8*)(ob)     = *(const bf16x8*)&Eo[rr * 72 + col0];
            *(bf16x8*)(ob + 8) = *(const bf16x8*)&Eo[rr * 72 + col0 + 8];
        }
        if (low == 0) {
#pragma unroll
            for (int r = 0; r < 4; ++r)
                lpart[pidx * 64 + wave * 16 + quad * 4 + r] = ol[r];
        }
    }
}

// ---------------- Kernel 3: combine. out[b,qb] = sum_J Opart(b,qb,J) / sum_J lpart.
__global__ __launch_bounds__(256) void attn_combine(const bf16* __restrict__ Opart,
                                                    const float* __restrict__ lpart,
                                                    float* __restrict__ out) {
    const int tile = blockIdx.x;         // b*32+qb
    const int qb   = tile & 31;
    const int nJ   = (qb >> 1) + 1;
    const int tid  = threadIdx.x;
    const int row  = tid >> 2;           // 0..63
    const int col0 = (tid & 3) * 16;

    float l = 0.f;
    for (int ch = 0; ch < nJ; ++ch) l += lpart[((long)tile * 16 + ch) * 64 + row];
    float rl = 1.0f / l;

    float s[16];
#pragma unroll
    for (int i = 0; i < 16; ++i) s[i] = 0.f;
    for (int ch = 0; ch < nJ; ++ch) {
        const bf16* ob = Opart + ((long)tile * 16 + ch) * 4096 + row * 64 + col0;
        bf16x8 u0 = *(const bf16x8*)(ob);
        bf16x8 u1 = *(const bf16x8*)(ob + 8);
#pragma unroll
        for (int i = 0; i < 8; ++i) { s[i] += (float)u0[i]; s[8 + i] += (float)u1[i]; }
    }
    float4* op = (float4*)(out + (long)tile * 4096 + row * 64 + col0);
#pragma unroll
    for (int v = 0; v < 4; ++v) {
        float4 w;
        w.x = s[v * 4 + 0] * rl; w.y = s[v * 4 + 1] * rl;
        w.z = s[v * 4 + 2] * rl; w.w = s[v * 4 + 3] * rl;
        op[v] = w;
    }
}

extern "C" void kernel_launch(void* const* d_in, const int* in_sizes, int n_in,
                              void* d_out, int out_size, void* d_ws, size_t ws_size,
                              hipStream_t stream) {
    const float* x  = (const float*)d_in[0];
    const float* Wk = (const float*)d_in[1];
    const float* Wv = (const float*)d_in[2];
    float* out = (float*)d_out;

    char* ws = (char*)d_ws;
    bf16*  Wb    = (bf16*)ws;                           // 256 KB
    bf16*  Kbuf  = (bf16*)(ws + (1 << 20));             // 2 MB
    bf16*  Vt    = (bf16*)(ws + (3 << 20));             // 2 MB
    bf16*  Opart = (bf16*)(ws + (5 << 20));             // 256*16*4096*2 = 32 MB
    float* lpart = (float*)(ws + (40 << 20));           // 1 MB

    wconv_kernel<<<128, 256, 0, stream>>>(Wk, Wv, Wb);
    proj_kernel<<<512, 256, 0, stream>>>(x, Wb, Kbuf, Vt);
    attn_kernel<<<8 * 136, 256, 0, stream>>>(Kbuf, Vt, Opart, lpart);
    attn_combine<<<256, 256, 0, stream>>>(Opart, lpart, out);
}